// Round 2
// baseline (837.111 us; speedup 1.0000x reference)
//
#include <hip/hip_runtime.h>
#include <hip/hip_bf16.h>

typedef __bf16 bf16;
typedef __attribute__((ext_vector_type(8))) __bf16 bf16x8;
typedef __attribute__((ext_vector_type(4))) float floatx4;

#define B_  4
#define C_  512
#define H_  96
#define W_  96
#define HD_ 64
#define HW_ 9216
#define BH_ 32
#define SCALING_ 0.125f

static constexpr size_t T_ELEMS = (size_t)BH_ * HD_ * HW_;   // 18,874,368 elems per array
static constexpr size_t S_ELEMS = (size_t)BH_ * HW_;         // 294,912 stat elems

// ---------------------------------------------------------------------------
// Kernel 1: 1x1 conv GEMM (fp32 in -> bf16 MFMA -> bf16 out).
// out[b,o,p] = (sum_c W[o,c]*src[b,c,p] + bias[o]) * scale
// grid: (144 pos-tiles, 8 o-tiles, 12 = arr*4 + b), block 256 (4 waves)
// ---------------------------------------------------------------------------
__global__ __launch_bounds__(256) void conv_gemm(
    const float* __restrict__ q, const float* __restrict__ v,
    const float* __restrict__ Wq, const float* __restrict__ bq,
    const float* __restrict__ Wk, const float* __restrict__ bk,
    const float* __restrict__ Wv, const float* __restrict__ bv,
    bf16* __restrict__ t, bf16* __restrict__ f, bf16* __restrict__ g)
{
    const int z   = blockIdx.z;
    const int arr = z >> 2;        // 0=t, 1=f, 2=g
    const int b   = z & 3;
    const float* src  = (arr == 2) ? v : q;
    const float* Wm   = (arr == 0) ? Wq : (arr == 1) ? Wk : Wv;
    const float* bias = (arr == 0) ? bq : (arr == 1) ? bk : bv;
    bf16* dst         = (arr == 0) ? t  : (arr == 1) ? f  : g;
    const float scale = (arr == 0) ? SCALING_ : 1.0f;

    const int p0 = blockIdx.x * 64;
    const int o0 = blockIdx.y * 64;

    __shared__ __align__(16) bf16 As[64][40];   // A[m][k], pad stride 40 (80B)
    __shared__ __align__(16) bf16 Bs[64][40];   // B^T[n][k]

    const int tid   = threadIdx.x;
    const int lane  = tid & 63;
    const int wave  = tid >> 6;
    const int lquad = lane >> 4;
    const int l16   = lane & 15;

    floatx4 acc[4] = {};

    const float* srcb = src + (size_t)b * C_ * HW_;

    const int am = tid >> 2;          // 0..63  (row of A tile)
    const int ak = (tid & 3) * 8;     // 0,8,16,24
    const int bp = tid & 63;          // pos lane
    const int bc = (tid >> 6) * 8;    // c group base

    for (int k0 = 0; k0 < C_; k0 += 32) {
        // A tile: Wm[o0+am][k0+ak..+8)  (fp32, two 16B loads), convert to bf16
        const float4 a0 = *(const float4*)(Wm + (size_t)(o0 + am) * C_ + k0 + ak);
        const float4 a1 = *(const float4*)(Wm + (size_t)(o0 + am) * C_ + k0 + ak + 4);
        bf16 ar[8] __attribute__((aligned(16)));
        ar[0] = (bf16)a0.x; ar[1] = (bf16)a0.y; ar[2] = (bf16)a0.z; ar[3] = (bf16)a0.w;
        ar[4] = (bf16)a1.x; ar[5] = (bf16)a1.y; ar[6] = (bf16)a1.z; ar[7] = (bf16)a1.w;
        *(uint4*)&As[am][ak] = *(const uint4*)ar;
        // B tile: src[b][k0+bc+j][p0+bp] -> Bs[pos][c] (coalesced across bp)
        bf16 br[8] __attribute__((aligned(16)));
        #pragma unroll
        for (int j = 0; j < 8; j++)
            br[j] = (bf16)srcb[(size_t)(k0 + bc + j) * HW_ + p0 + bp];
        *(uint4*)&Bs[bp][bc] = *(const uint4*)br;
        __syncthreads();

        bf16x8 afrag = *(const bf16x8*)&As[wave * 16 + l16][lquad * 8];
        #pragma unroll
        for (int nt = 0; nt < 4; nt++) {
            bf16x8 bfrag = *(const bf16x8*)&Bs[nt * 16 + l16][lquad * 8];
            acc[nt] = __builtin_amdgcn_mfma_f32_16x16x32_bf16(afrag, bfrag, acc[nt], 0, 0, 0);
        }
        __syncthreads();
    }

    bf16* dstb = dst + (size_t)b * C_ * HW_;
    #pragma unroll
    for (int nt = 0; nt < 4; nt++) {
        const int col = p0 + nt * 16 + l16;
        #pragma unroll
        for (int r = 0; r < 4; r++) {
            const int row = o0 + wave * 16 + lquad * 4 + r;
            float val = (acc[nt][r] + bias[row]) * scale;
            dstb[(size_t)row * HW_ + col] = (bf16)val;
        }
    }
}

// ---------------------------------------------------------------------------
// Kernel 2: batched 96x96 plane transpose for t,f,g -> tT,fT,gT (bf16)
// grid: (9 tiles, 2048 planes, 3 arrays), block 256
// ---------------------------------------------------------------------------
__global__ __launch_bounds__(256) void transpose3(const bf16* __restrict__ src, bf16* __restrict__ dst)
{
    const int arr   = blockIdx.z;
    const int plane = blockIdx.y;          // bh*64 + d
    const int tile  = blockIdx.x;          // 0..8
    const int ty0 = (tile / 3) * 32, tx0 = (tile % 3) * 32;
    const bf16* s = src + (size_t)arr * T_ELEMS + (size_t)plane * HW_;
    bf16*       d = dst + (size_t)arr * T_ELEMS + (size_t)plane * HW_;

    __shared__ bf16 tb[32][33];
    const int tid = threadIdx.x;
    const int lx = tid & 31, lrow = tid >> 5;   // 8 rows/pass

    #pragma unroll
    for (int ss = 0; ss < 4; ss++) {
        int a = lrow + ss * 8;
        tb[a][lx] = s[(ty0 + a) * W_ + tx0 + lx];
    }
    __syncthreads();
    #pragma unroll
    for (int ss = 0; ss < 4; ss++) {
        int a = lrow + ss * 8;
        d[(tx0 + a) * H_ + ty0 + lx] = tb[lx][a];
    }
}

// ---------------------------------------------------------------------------
// Kernel 3/4: axis attention (row: IS_COL=false on t,f,g; col: IS_COL=true on
// tT,fT,gT).  Block per (bh, q0) slice; computes e (96x96, K=64), partial
// softmax stats (m,l), unnormalized partial output (64x96). grid (96,32).
// LDS = 57.6 KB (bf16 tiles) -> safe under a 64 KB/block limit.
// ---------------------------------------------------------------------------
template <bool IS_COL>
__global__ __launch_bounds__(256) void attn_axis(
    const bf16* __restrict__ tp, const bf16* __restrict__ fp, const bf16* __restrict__ gp,
    bf16* __restrict__ outp, float* __restrict__ mstat, float* __restrict__ lstat)
{
    const int q0 = blockIdx.x;   // y for row-kernel, x for col-kernel
    const int bh = blockIdx.y;

    __shared__ bf16 tl[64][100];
    __shared__ bf16 fl[64][100];
    __shared__ bf16 gl[64][100];
    __shared__ bf16 el[96][100];

    const int tid = threadIdx.x;
    const size_t base = (size_t)bh * (HD_ * HW_) + (size_t)q0 * 96;

    // stage 64x96 slices (contiguous inner dim)
    for (int i = tid; i < 64 * 96; i += 256) {
        int d = i / 96, j = i % 96;
        size_t gi = base + (size_t)d * HW_ + j;
        tl[d][j] = tp[gi];
        fl[d][j] = fp[gi];
        gl[d][j] = gp[gi];
    }
    __syncthreads();

    // e[j][i] = sum_d tl[d][j] * fl[d][i]   (96x96x64)
    {
        const int tx = tid & 15, ty = tid >> 4;
        const int x0 = tx * 6, i0 = ty * 6;
        float acc[6][6] = {};
        for (int d = 0; d < 64; d++) {
            float tv[6], fv[6];
            #pragma unroll
            for (int c = 0; c < 6; c++) tv[c] = (float)tl[d][x0 + c];
            #pragma unroll
            for (int c = 0; c < 6; c++) fv[c] = (float)fl[d][i0 + c];
            #pragma unroll
            for (int a = 0; a < 6; a++)
                #pragma unroll
                for (int c = 0; c < 6; c++)
                    acc[a][c] += tv[a] * fv[c];
        }
        #pragma unroll
        for (int a = 0; a < 6; a++)
            #pragma unroll
            for (int c = 0; c < 6; c++)
                el[x0 + a][i0 + c] = (bf16)acc[a][c];
    }
    __syncthreads();

    // per-row partial softmax; overwrite el with p = exp(e - m)
    if (tid < 96) {
        const int r = tid;
        if (IS_COL) el[r][r] = (bf16)(-1e30f);   // diagonal mask (i == y)
        float m = -1e30f;
        for (int i = 0; i < 96; i++) m = fmaxf(m, (float)el[r][i]);
        float s = 0.f;
        for (int i = 0; i < 96; i++) {
            float p = __expf((float)el[r][i] - m);
            el[r][i] = (bf16)p;
            s += p;
        }
        size_t sidx = IS_COL ? ((size_t)bh * HW_ + (size_t)r * 96 + q0)
                             : ((size_t)bh * HW_ + (size_t)q0 * 96 + r);
        mstat[sidx] = m;
        lstat[sidx] = s;
    }
    __syncthreads();

    // out[d][j] = sum_i p[j][i] * gl[d][i]   (64x96x96)
    {
        const int td = tid & 15, tj = tid >> 4;
        const int d0 = td * 4, j0 = tj * 6;
        float acc[4][6] = {};
        for (int i = 0; i < 96; i++) {
            float gv[4], pv[6];
            #pragma unroll
            for (int a = 0; a < 4; a++) gv[a] = (float)gl[d0 + a][i];
            #pragma unroll
            for (int c = 0; c < 6; c++) pv[c] = (float)el[j0 + c][i];
            #pragma unroll
            for (int a = 0; a < 4; a++)
                #pragma unroll
                for (int c = 0; c < 6; c++)
                    acc[a][c] += gv[a] * pv[c];
        }
        #pragma unroll
        for (int a = 0; a < 4; a++)
            #pragma unroll
            for (int c = 0; c < 6; c++)
                outp[base + (size_t)(d0 + a) * HW_ + j0 + c] = (bf16)acc[a][c];
    }
}

// ---------------------------------------------------------------------------
// Kernel 5: merge row/col partials, apply gamma*out + v  (fp32 output)
// ---------------------------------------------------------------------------
__global__ __launch_bounds__(256) void merge_kernel(
    const bf16* __restrict__ outr, const bf16* __restrict__ outcT,
    const float* __restrict__ mr, const float* __restrict__ lr,
    const float* __restrict__ mc, const float* __restrict__ lc,
    const float* __restrict__ v, const float* __restrict__ gamma, float* __restrict__ out)
{
    const size_t idx = (size_t)blockIdx.x * 256 + threadIdx.x;   // < T_ELEMS
    const int plane = (int)(idx / HW_);        // bh*64 + d
    const int yx    = (int)(idx % HW_);
    const int y = yx / 96, x = yx % 96;
    const size_t sidx = (size_t)(plane >> 6) * HW_ + yx;

    float m_r = mr[sidx], l_r = lr[sidx];
    float m_c = mc[sidx], l_c = lc[sidx];
    float m  = fmaxf(m_r, m_c);
    float wr = __expf(m_r - m), wc = __expf(m_c - m);
    float denom = l_r * wr + l_c * wc;

    float orv = (float)outr[idx];
    float ocv = (float)outcT[(size_t)plane * HW_ + (size_t)x * 96 + y];
    float val = (orv * wr + ocv * wc) / denom;
    out[idx] = gamma[0] * val + v[idx];
}

// ---------------------------------------------------------------------------
extern "C" void kernel_launch(void* const* d_in, const int* in_sizes, int n_in,
                              void* d_out, int out_size, void* d_ws, size_t ws_size,
                              hipStream_t stream)
{
    const float* q     = (const float*)d_in[0];
    const float* v     = (const float*)d_in[1];
    const float* Wq    = (const float*)d_in[2];
    const float* bq    = (const float*)d_in[3];
    const float* Wk    = (const float*)d_in[4];
    const float* bk    = (const float*)d_in[5];
    const float* Wv    = (const float*)d_in[6];
    const float* bv    = (const float*)d_in[7];
    const float* gamma = (const float*)d_in[8];
    float* out = (float*)d_out;

    char* w = (char*)d_ws;
    const size_t Tb = T_ELEMS * sizeof(bf16);   // 37,748,736 B
    bf16* t    = (bf16*)(w + 0 * Tb);
    bf16* f    = (bf16*)(w + 1 * Tb);
    bf16* g    = (bf16*)(w + 2 * Tb);
    bf16* tT   = (bf16*)(w + 3 * Tb);
    bf16* fT   = (bf16*)(w + 4 * Tb);
    bf16* gT   = (bf16*)(w + 5 * Tb);
    bf16* outr = (bf16*)(w + 6 * Tb);
    float* mr  = (float*)(w + 7 * Tb);          // row stats beyond 7*Tb (2.36 MB)
    float* lr  = mr + S_ELEMS;
    // col stats overlay f's region (f dead after row attention)
    float* mc  = (float*)(w + 1 * Tb);
    float* lc  = mc + S_ELEMS;
    // col partial output overlays t's region (t dead after row attention)
    bf16* outcT = (bf16*)(w + 0 * Tb);
    // high-water: 7*Tb + 2*S*4 = 266,600,448 B  (< 256 MiB)

    // 1) t, f, g  (fp32 in, bf16 out)
    conv_gemm<<<dim3(HW_ / 64, C_ / 64, 12), 256, 0, stream>>>(q, v, Wq, bq, Wk, bk, Wv, bv, t, f, g);
    // 2) transposed copies
    transpose3<<<dim3(9, BH_ * HD_, 3), 256, 0, stream>>>(t, tT);
    // 3) row attention partials
    attn_axis<false><<<dim3(96, BH_), 256, 0, stream>>>(t, f, g, outr, mr, lr);
    // 4) col attention partials (transposed arrays; writes outcT over t, stats over f)
    attn_axis<true><<<dim3(96, BH_), 256, 0, stream>>>(tT, fT, gT, outcT, mc, lc);
    // 5) merge + residual (fp32 output)
    merge_kernel<<<dim3((unsigned)(T_ELEMS / 256)), 256, 0, stream>>>(outr, outcT, mr, lr, mc, lc, v, gamma, out);
}

// Round 3
// 494.031 us; speedup vs baseline: 1.6944x; 1.6944x over previous
//
#include <hip/hip_runtime.h>
#include <hip/hip_bf16.h>

typedef __bf16 bf16;
typedef __attribute__((ext_vector_type(8))) __bf16 bf16x8;
typedef __attribute__((ext_vector_type(4))) float floatx4;

#define B_  4
#define C_  512
#define H_  96
#define W_  96
#define HD_ 64
#define HW_ 9216
#define BH_ 32
#define SCALING_ 0.125f

static constexpr size_t T_ELEMS = (size_t)BH_ * HD_ * HW_;   // 18,874,368 elems per array
static constexpr size_t S_ELEMS = (size_t)BH_ * HW_;         // 294,912 stat elems

// ---------------------------------------------------------------------------
// Kernel 0a: cast weights fp32 -> bf16, concatenated Wb[3][512][512]
// ---------------------------------------------------------------------------
__global__ __launch_bounds__(256) void cast_w(
    const float* __restrict__ Wq, const float* __restrict__ Wk, const float* __restrict__ Wv,
    bf16* __restrict__ Wb)
{
    const int i  = blockIdx.x * 256 + threadIdx.x;   // < 196608
    const int e0 = i * 4;
    const int arr = e0 >> 18;                        // /262144
    const int off = e0 & 262143;
    const float* W = (arr == 0) ? Wq : (arr == 1) ? Wk : Wv;
    const float4 val = *(const float4*)(W + off);
    bf16 tmp[4] __attribute__((aligned(8)));
    tmp[0] = (bf16)val.x; tmp[1] = (bf16)val.y; tmp[2] = (bf16)val.z; tmp[3] = (bf16)val.w;
    *(uint2*)(Wb + e0) = *(const uint2*)tmp;
}

// ---------------------------------------------------------------------------
// Kernel 0b: cast + transpose q,v fp32 [b][c][p] -> bf16 [b][p][c]
// grid (144, 8, 8=src*4+b), block 256; 64x64 tiles via LDS
// ---------------------------------------------------------------------------
__global__ __launch_bounds__(256) void cast_qv(
    const float* __restrict__ q, const float* __restrict__ v,
    bf16* __restrict__ qbT, bf16* __restrict__ vbT)
{
    const int z = blockIdx.z;
    const int s = z >> 2, b = z & 3;
    const float* sb = (s ? v : q) + (size_t)b * C_ * HW_;
    bf16*       db = (s ? vbT : qbT) + (size_t)b * HW_ * C_;
    const int p0 = blockIdx.x * 64, c0 = blockIdx.y * 64;

    __shared__ float ts[64][65];
    const int tid = threadIdx.x;

    for (int i = tid; i < 1024; i += 256) {          // 64 rows x 16 float4
        const int row = i >> 4, seg = i & 15;
        const float4 val = *(const float4*)(sb + (size_t)(c0 + row) * HW_ + p0 + seg * 4);
        ts[row][seg * 4 + 0] = val.x; ts[row][seg * 4 + 1] = val.y;
        ts[row][seg * 4 + 2] = val.z; ts[row][seg * 4 + 3] = val.w;
    }
    __syncthreads();
    for (int i = tid; i < 512; i += 256) {           // 64 p-rows x 8 uint4
        const int prow = i >> 3, cseg = i & 7;
        bf16 tmp[8] __attribute__((aligned(16)));
        #pragma unroll
        for (int k = 0; k < 8; k++) tmp[k] = (bf16)ts[cseg * 8 + k][prow];
        *(uint4*)(db + (size_t)(p0 + prow) * C_ + c0 + cseg * 8) = *(const uint4*)tmp;
    }
}

// ---------------------------------------------------------------------------
// Kernel 1: 1x1 conv GEMM, m97 structure: 128x128 tile, BK=32,
// global_load_lds width-16 staging, 16 MFMA / 8 ds_read_b128 per wave-kiter.
// A = Wb[arr] row-major [o][c]; B^T = qbT/vbT row-major [p][c].
// grid (72, 4, 12 = arr*4+b), block 256.
// ---------------------------------------------------------------------------
__global__ __launch_bounds__(256) void conv_mfma(
    const bf16* __restrict__ Wb,
    const float* __restrict__ bq, const float* __restrict__ bk, const float* __restrict__ bv,
    const bf16* __restrict__ qbT, const bf16* __restrict__ vbT,
    bf16* __restrict__ t, bf16* __restrict__ f, bf16* __restrict__ g)
{
    const int z = blockIdx.z, arr = z >> 2, b = z & 3;
    const bf16* A    = Wb + (size_t)arr * C_ * C_;
    const bf16* Bsrc = ((arr == 2) ? vbT : qbT) + (size_t)b * HW_ * C_;
    const float* bias = (arr == 0) ? bq : (arr == 1) ? bk : bv;
    bf16* dst = ((arr == 0) ? t : (arr == 1) ? f : g) + (size_t)b * C_ * HW_;
    const float scale = (arr == 0) ? SCALING_ : 1.0f;

    const int p0 = blockIdx.x * 128;
    const int o0 = blockIdx.y * 128;

    __shared__ __align__(16) bf16 As[128 * 32];   // [o][k] flat
    __shared__ __align__(16) bf16 Bs[128 * 32];   // [p][k] flat

    const int tid = threadIdx.x, lane = tid & 63;
    const int wave = tid >> 6, l16 = lane & 15, quad = lane >> 4;
    const int mrow = (wave >> 1) * 64, ncol = (wave & 1) * 64;

    floatx4 acc[4][4] = {};

    for (int k0 = 0; k0 < C_; k0 += 32) {
        #pragma unroll
        for (int c = tid; c < 512; c += 256) {            // 512 16B chunks per tile
            const int row = c >> 2, seg = c & 3;
            const bf16* gA = A    + (size_t)(o0 + row) * C_ + k0 + seg * 8;
            const bf16* gB = Bsrc + (size_t)(p0 + row) * C_ + k0 + seg * 8;
#if __has_builtin(__builtin_amdgcn_global_load_lds)
            char* lA = (char*)As + (size_t)(c & ~63) * 16;   // wave-uniform base
            char* lB = (char*)Bs + (size_t)(c & ~63) * 16;
            __builtin_amdgcn_global_load_lds((const __attribute__((address_space(1))) void*)gA,
                                             (__attribute__((address_space(3))) void*)lA, 16, 0, 0);
            __builtin_amdgcn_global_load_lds((const __attribute__((address_space(1))) void*)gB,
                                             (__attribute__((address_space(3))) void*)lB, 16, 0, 0);
#else
            *(uint4*)((char*)As + (size_t)c * 16) = *(const uint4*)gA;
            *(uint4*)((char*)Bs + (size_t)c * 16) = *(const uint4*)gB;
#endif
        }
        __syncthreads();
        bf16x8 af[4], bf_[4];
        #pragma unroll
        for (int i = 0; i < 4; i++)
            af[i] = *(const bf16x8*)&As[(mrow + i * 16 + l16) * 32 + quad * 8];
        #pragma unroll
        for (int j = 0; j < 4; j++)
            bf_[j] = *(const bf16x8*)&Bs[(ncol + j * 16 + l16) * 32 + quad * 8];
        #pragma unroll
        for (int i = 0; i < 4; i++)
            #pragma unroll
            for (int j = 0; j < 4; j++)
                acc[i][j] = __builtin_amdgcn_mfma_f32_16x16x32_bf16(af[i], bf_[j], acc[i][j], 0, 0, 0);
        __syncthreads();
    }

    #pragma unroll
    for (int i = 0; i < 4; i++)
        #pragma unroll
        for (int r = 0; r < 4; r++) {
            const int o = o0 + mrow + i * 16 + quad * 4 + r;
            const float bi = bias[o];
            #pragma unroll
            for (int j = 0; j < 4; j++) {
                const int p = p0 + ncol + j * 16 + l16;
                dst[(size_t)o * HW_ + p] = (bf16)((acc[i][j][r] + bi) * scale);
            }
        }
}

// ---------------------------------------------------------------------------
// Kernel 2: batched 96x96 plane transpose for t,f,g -> tT,fT,gT (bf16)
// ---------------------------------------------------------------------------
__global__ __launch_bounds__(256) void transpose3(const bf16* __restrict__ src, bf16* __restrict__ dst)
{
    const int arr   = blockIdx.z;
    const int plane = blockIdx.y;
    const int tile  = blockIdx.x;
    const int ty0 = (tile / 3) * 32, tx0 = (tile % 3) * 32;
    const bf16* s = src + (size_t)arr * T_ELEMS + (size_t)plane * HW_;
    bf16*       d = dst + (size_t)arr * T_ELEMS + (size_t)plane * HW_;

    __shared__ bf16 tb[32][33];
    const int tid = threadIdx.x;
    const int lx = tid & 31, lrow = tid >> 5;

    #pragma unroll
    for (int ss = 0; ss < 4; ss++) {
        int a = lrow + ss * 8;
        tb[a][lx] = s[(ty0 + a) * W_ + tx0 + lx];
    }
    __syncthreads();
    #pragma unroll
    for (int ss = 0; ss < 4; ss++) {
        int a = lrow + ss * 8;
        d[(tx0 + a) * H_ + ty0 + lx] = tb[lx][a];
    }
}

// ---------------------------------------------------------------------------
// Kernel 3/4: axis attention with MFMA.
// e[j][i] = sum_d t^T[j][d] * f[i][d]  (M=96,N=96,K=64)
// out[j][d] = sum_i p[j][i] * g[d][i]  (M=96,N=64,K=96)
// LDS: tl[j][d], fl[i][d] transposed; gl[d][i] natural; el raw-e then p.
// grid (96, 32), block 256.
// ---------------------------------------------------------------------------
template <bool IS_COL>
__global__ __launch_bounds__(256) void attn_mfma(
    const bf16* __restrict__ tp, const bf16* __restrict__ fp, const bf16* __restrict__ gp,
    bf16* __restrict__ outp, float* __restrict__ mstat, float* __restrict__ lstat)
{
    const int q0 = blockIdx.x;
    const int bh = blockIdx.y;

    __shared__ __align__(16) bf16 tl[96][72];    // [j][d]
    __shared__ __align__(16) bf16 fl[96][72];    // [i][d]
    __shared__ __align__(16) bf16 gl[64][104];   // [d][i]
    __shared__ __align__(16) bf16 el[96][104];   // [j][i]

    const int tid = threadIdx.x;
    const size_t base = (size_t)bh * (HD_ * HW_) + (size_t)q0 * 96;

    // stage: tl/fl transposed (vector global read, scalar LDS scatter), gl natural
    {
        const int d = tid >> 2, jo = tid & 3;
        #pragma unroll
        for (int s = 0; s < 3; s++) {
            const int j0 = jo * 24 + s * 8;
            const size_t gi = base + (size_t)d * HW_ + j0;
            bf16 tv[8] __attribute__((aligned(16)));
            bf16 fv[8] __attribute__((aligned(16)));
            *(uint4*)tv = *(const uint4*)(tp + gi);
            *(uint4*)fv = *(const uint4*)(fp + gi);
            #pragma unroll
            for (int k = 0; k < 8; k++) { tl[j0 + k][d] = tv[k]; fl[j0 + k][d] = fv[k]; }
        }
        for (int i = tid; i < 768; i += 256) {   // 64 rows x 12 uint4
            const int row = i / 12, seg = i % 12;
            *(uint4*)&gl[row][seg * 8] = *(const uint4*)(gp + base + (size_t)row * HW_ + seg * 8);
        }
    }
    __syncthreads();

    const int lane = tid & 63, wave = tid >> 6;
    const int l16 = lane & 15, quad = lane >> 4;

    // e-GEMM: 36 16x16 tiles, 2 k-steps each
    #pragma unroll
    for (int it = 0; it < 9; it++) {
        const int idx = wave + it * 4;
        const int mt = idx / 6, nt = idx % 6;
        floatx4 a = {};
        #pragma unroll
        for (int ks = 0; ks < 2; ks++) {
            bf16x8 af = *(const bf16x8*)&tl[mt * 16 + l16][ks * 32 + quad * 8];
            bf16x8 bf_ = *(const bf16x8*)&fl[nt * 16 + l16][ks * 32 + quad * 8];
            a = __builtin_amdgcn_mfma_f32_16x16x32_bf16(af, bf_, a, 0, 0, 0);
        }
        #pragma unroll
        for (int r = 0; r < 4; r++)
            el[mt * 16 + quad * 4 + r][nt * 16 + l16] = (bf16)a[r];
    }
    __syncthreads();

    // partial softmax per row
    if (tid < 96) {
        const int r = tid;
        if (IS_COL) el[r][r] = (bf16)(-1e30f);
        float m = -1e30f;
        for (int i = 0; i < 96; i++) m = fmaxf(m, (float)el[r][i]);
        float s = 0.f;
        for (int i = 0; i < 96; i++) {
            float p = __expf((float)el[r][i] - m);
            el[r][i] = (bf16)p;
            s += p;
        }
        const size_t sidx = IS_COL ? ((size_t)bh * HW_ + (size_t)r * 96 + q0)
                                   : ((size_t)bh * HW_ + (size_t)q0 * 96 + r);
        mstat[sidx] = m;
        lstat[sidx] = s;
    }
    __syncthreads();

    // PV-GEMM: out[j][d], 24 tiles, 3 k-steps; C-frags staged to ol=[d][j] (overlays tl)
    bf16 (*ol)[104] = (bf16 (*)[104])tl;         // 64*104*2 = 13312 <= sizeof(tl)
    #pragma unroll
    for (int it = 0; it < 6; it++) {
        const int idx = wave + it * 4;
        const int mt = idx / 4, nt = idx % 4;
        floatx4 a = {};
        #pragma unroll
        for (int ks = 0; ks < 3; ks++) {
            bf16x8 pf = *(const bf16x8*)&el[mt * 16 + l16][ks * 32 + quad * 8];
            bf16x8 gf = *(const bf16x8*)&gl[nt * 16 + l16][ks * 32 + quad * 8];
            a = __builtin_amdgcn_mfma_f32_16x16x32_bf16(pf, gf, a, 0, 0, 0);
        }
        #pragma unroll
        for (int r = 0; r < 4; r++)
            ol[nt * 16 + l16][mt * 16 + quad * 4 + r] = (bf16)a[r];
    }
    __syncthreads();

    // coalesced 16B global stores from ol
    for (int i = tid; i < 768; i += 256) {
        const int row = i / 12, seg = i % 12;
        *(uint4*)(outp + base + (size_t)row * HW_ + seg * 8) = *(const uint4*)&ol[row][seg * 8];
    }
}

// ---------------------------------------------------------------------------
// Kernel 5: merge row/col partials per plane (LDS transpose of outcT),
// apply gamma*out + v.  grid 2048 blocks (one per plane), block 256.
// ---------------------------------------------------------------------------
__global__ __launch_bounds__(256) void merge2(
    const bf16* __restrict__ outr, const bf16* __restrict__ outcT,
    const float* __restrict__ mr, const float* __restrict__ lr,
    const float* __restrict__ mc, const float* __restrict__ lc,
    const float* __restrict__ v, const float* __restrict__ gamma, float* __restrict__ out)
{
    const int plane = blockIdx.x;                // bh*64 + d
    const int bh = plane >> 6;
    const int tid = threadIdx.x;

    __shared__ __align__(16) bf16 ocl[96][104];  // outcT plane: [x][y]
    for (int i = tid; i < 1152; i += 256) {      // 96 rows x 12 uint4
        const int row = i / 12, seg = i % 12;
        *(uint4*)&ocl[row][seg * 8] = *(const uint4*)(outcT + (size_t)plane * HW_ + row * 96 + seg * 8);
    }
    __syncthreads();

    const float gam = gamma[0];
    for (int idx = tid; idx < HW_; idx += 256) {
        const int y = idx / 96, x = idx % 96;
        const size_t sidx = (size_t)bh * HW_ + idx;
        const float m_r = mr[sidx], l_r = lr[sidx];
        const float m_c = mc[sidx], l_c = lc[sidx];
        const float m  = fmaxf(m_r, m_c);
        const float wr = __expf(m_r - m), wc = __expf(m_c - m);
        const float denom = l_r * wr + l_c * wc;

        const float orv = (float)outr[(size_t)plane * HW_ + idx];
        const float ocv = (float)ocl[x][y];
        const float val = (orv * wr + ocv * wc) / denom;
        out[(size_t)plane * HW_ + idx] = gam * val + v[(size_t)plane * HW_ + idx];
    }
}

// ---------------------------------------------------------------------------
extern "C" void kernel_launch(void* const* d_in, const int* in_sizes, int n_in,
                              void* d_out, int out_size, void* d_ws, size_t ws_size,
                              hipStream_t stream)
{
    const float* q     = (const float*)d_in[0];
    const float* v     = (const float*)d_in[1];
    const float* Wq    = (const float*)d_in[2];
    const float* bq    = (const float*)d_in[3];
    const float* Wk    = (const float*)d_in[4];
    const float* bk    = (const float*)d_in[5];
    const float* Wv    = (const float*)d_in[6];
    const float* bv    = (const float*)d_in[7];
    const float* gamma = (const float*)d_in[8];
    float* out = (float*)d_out;

    char* w = (char*)d_ws;
    const size_t Tb = T_ELEMS * sizeof(bf16);   // 37,748,736 B
    bf16* t    = (bf16*)(w + 0 * Tb);
    bf16* f    = (bf16*)(w + 1 * Tb);
    bf16* g    = (bf16*)(w + 2 * Tb);
    bf16* tT   = (bf16*)(w + 3 * Tb);
    bf16* fT   = (bf16*)(w + 4 * Tb);
    bf16* gT   = (bf16*)(w + 5 * Tb);
    bf16* outr = (bf16*)(w + 6 * Tb);
    float* mr  = (float*)(w + 7 * Tb);
    float* lr  = mr + S_ELEMS;
    // overlays (lifetimes verified):
    bf16* qbT  = (bf16*)(w + 3 * Tb);   // dead after conv; clobbered by tT
    bf16* vbT  = (bf16*)(w + 4 * Tb);   // dead after conv; clobbered by fT
    bf16* Wb   = (bf16*)(w + 5 * Tb);   // dead after conv; clobbered by gT
    float* mc  = (float*)(w + 1 * Tb);  // overlays f (dead after attn_row)
    float* lc  = mc + S_ELEMS;
    bf16* outcT = (bf16*)(w + 0 * Tb);  // overlays t (dead after attn_row)
    // high-water: 7*Tb + 2*S_ELEMS*4 = 266,600,448 B (unchanged from passing run)

    cast_w  <<<dim3(768), 256, 0, stream>>>(Wq, Wk, Wv, Wb);
    cast_qv <<<dim3(144, 8, 8), 256, 0, stream>>>(q, v, qbT, vbT);
    conv_mfma<<<dim3(72, 4, 12), 256, 0, stream>>>(Wb, bq, bk, bv, qbT, vbT, t, f, g);
    transpose3<<<dim3(9, BH_ * HD_, 3), 256, 0, stream>>>(t, tT);
    attn_mfma<false><<<dim3(96, BH_), 256, 0, stream>>>(t, f, g, outr, mr, lr);
    attn_mfma<true> <<<dim3(96, BH_), 256, 0, stream>>>(tT, fT, gT, outcT, mc, lc);
    merge2<<<dim3(BH_ * HD_), 256, 0, stream>>>(outr, outcT, mr, lr, mc, lc, v, gamma, out);
}

// Round 4
// 448.755 us; speedup vs baseline: 1.8654x; 1.1009x over previous
//
#include <hip/hip_runtime.h>
#include <hip/hip_bf16.h>

typedef __bf16 bf16;
typedef __attribute__((ext_vector_type(8))) __bf16 bf16x8;
typedef __attribute__((ext_vector_type(4))) float floatx4;

#define B_  4
#define C_  512
#define H_  96
#define W_  96
#define HD_ 64
#define HW_ 9216
#define BH_ 32
#define SCALING_ 0.125f
#define BHS_ 589824          // 96*96*64 elems per bh in d-inner layout

static constexpr size_t T_ELEMS = (size_t)BH_ * HD_ * HW_;   // 18,874,368
static constexpr size_t S_ELEMS = (size_t)BH_ * HW_;         // 294,912

// ---------------------------------------------------------------------------
// Kernel 0a: cast weights fp32 -> bf16, concatenated Wb[3][512][512]
// ---------------------------------------------------------------------------
__global__ __launch_bounds__(256) void cast_w(
    const float* __restrict__ Wq, const float* __restrict__ Wk, const float* __restrict__ Wv,
    bf16* __restrict__ Wb)
{
    const int i  = blockIdx.x * 256 + threadIdx.x;   // < 196608
    const int e0 = i * 4;
    const int arr = e0 >> 18;
    const int off = e0 & 262143;
    const float* W = (arr == 0) ? Wq : (arr == 1) ? Wk : Wv;
    const float4 val = *(const float4*)(W + off);
    bf16 tmp[4] __attribute__((aligned(8)));
    tmp[0] = (bf16)val.x; tmp[1] = (bf16)val.y; tmp[2] = (bf16)val.z; tmp[3] = (bf16)val.w;
    *(uint2*)(Wb + e0) = *(const uint2*)tmp;
}

// ---------------------------------------------------------------------------
// Kernel 0b: cast + transpose q,v fp32 [b][c][p] -> bf16 [b][p][c]
// ---------------------------------------------------------------------------
__global__ __launch_bounds__(256) void cast_qv(
    const float* __restrict__ q, const float* __restrict__ v,
    bf16* __restrict__ qbT, bf16* __restrict__ vbT)
{
    const int z = blockIdx.z;
    const int s = z >> 2, b = z & 3;
    const float* sb = (s ? v : q) + (size_t)b * C_ * HW_;
    bf16*       db = (s ? vbT : qbT) + (size_t)b * HW_ * C_;
    const int p0 = blockIdx.x * 64, c0 = blockIdx.y * 64;

    __shared__ float ts[64][65];
    const int tid = threadIdx.x;

    for (int i = tid; i < 1024; i += 256) {
        const int row = i >> 4, seg = i & 15;
        const float4 val = *(const float4*)(sb + (size_t)(c0 + row) * HW_ + p0 + seg * 4);
        ts[row][seg * 4 + 0] = val.x; ts[row][seg * 4 + 1] = val.y;
        ts[row][seg * 4 + 2] = val.z; ts[row][seg * 4 + 3] = val.w;
    }
    __syncthreads();
    for (int i = tid; i < 512; i += 256) {
        const int prow = i >> 3, cseg = i & 7;
        bf16 tmp[8] __attribute__((aligned(16)));
        #pragma unroll
        for (int k = 0; k < 8; k++) tmp[k] = (bf16)ts[cseg * 8 + k][prow];
        *(uint4*)(db + (size_t)(p0 + prow) * C_ + c0 + cseg * 8) = *(const uint4*)tmp;
    }
}

// ---------------------------------------------------------------------------
// Kernel 1: conv GEMM (m97 structure, 128x128 tile, BK=32).
// Outputs: arr 0 -> tR[bh][y][x][d] (*SCALING), arr 1 -> fR[bh][y][x][d],
//          arr 2 -> g[bh][d][y][x] natural.   All via LDS-tile epilogue.
// grid (72, 4, 12 = arr*4+b), block 256.
// ---------------------------------------------------------------------------
__global__ __launch_bounds__(256) void conv_mfma(
    const bf16* __restrict__ Wb,
    const float* __restrict__ bq, const float* __restrict__ bk, const float* __restrict__ bv,
    const bf16* __restrict__ qbT, const bf16* __restrict__ vbT,
    bf16* __restrict__ tR, bf16* __restrict__ fR, bf16* __restrict__ g)
{
    const int z = blockIdx.z, arr = z >> 2, b = z & 3;
    const bf16* A    = Wb + (size_t)arr * C_ * C_;
    const bf16* Bsrc = ((arr == 2) ? vbT : qbT) + (size_t)b * HW_ * C_;
    const float* bias = (arr == 0) ? bq : (arr == 1) ? bk : bv;
    const float scale = (arr == 0) ? SCALING_ : 1.0f;

    const int p0 = blockIdx.x * 128;
    const int o0 = blockIdx.y * 128;

    __shared__ __align__(16) bf16 smem[17408];   // 34816 B: As/Bs during loop, tile in epilogue
    bf16* As = smem;          // 128*32
    bf16* Bs = smem + 4096;   // 128*32

    const int tid = threadIdx.x, lane = tid & 63;
    const int wave = tid >> 6, l16 = lane & 15, quad = lane >> 4;
    const int mrow = (wave >> 1) * 64, ncol = (wave & 1) * 64;

    floatx4 acc[4][4] = {};

    for (int k0 = 0; k0 < C_; k0 += 32) {
        #pragma unroll
        for (int c = tid; c < 512; c += 256) {
            const int row = c >> 2, seg = c & 3;
            const bf16* gA = A    + (size_t)(o0 + row) * C_ + k0 + seg * 8;
            const bf16* gB = Bsrc + (size_t)(p0 + row) * C_ + k0 + seg * 8;
#if __has_builtin(__builtin_amdgcn_global_load_lds)
            char* lA = (char*)As + (size_t)(c & ~63) * 16;
            char* lB = (char*)Bs + (size_t)(c & ~63) * 16;
            __builtin_amdgcn_global_load_lds((const __attribute__((address_space(1))) void*)gA,
                                             (__attribute__((address_space(3))) void*)lA, 16, 0, 0);
            __builtin_amdgcn_global_load_lds((const __attribute__((address_space(1))) void*)gB,
                                             (__attribute__((address_space(3))) void*)lB, 16, 0, 0);
#else
            *(uint4*)((char*)As + (size_t)c * 16) = *(const uint4*)gA;
            *(uint4*)((char*)Bs + (size_t)c * 16) = *(const uint4*)gB;
#endif
        }
        __syncthreads();
        bf16x8 af[4], bf_[4];
        #pragma unroll
        for (int i = 0; i < 4; i++)
            af[i] = *(const bf16x8*)&As[(mrow + i * 16 + l16) * 32 + quad * 8];
        #pragma unroll
        for (int j = 0; j < 4; j++)
            bf_[j] = *(const bf16x8*)&Bs[(ncol + j * 16 + l16) * 32 + quad * 8];
        #pragma unroll
        for (int i = 0; i < 4; i++)
            #pragma unroll
            for (int j = 0; j < 4; j++)
                acc[i][j] = __builtin_amdgcn_mfma_f32_16x16x32_bf16(af[i], bf_[j], acc[i][j], 0, 0, 0);
        __syncthreads();
    }

    const int TS = 136;   // tile row stride (bf16), 272 B = 17x16B
    if (arr < 2) {
        // tileT[p_local][o_local]
        #pragma unroll
        for (int i = 0; i < 4; i++)
            #pragma unroll
            for (int r = 0; r < 4; r++) {
                const int ol_ = mrow + i * 16 + quad * 4 + r;
                const float bi = bias[o0 + ol_];
                #pragma unroll
                for (int j = 0; j < 4; j++) {
                    const int pl = ncol + j * 16 + l16;
                    smem[pl * TS + ol_] = (bf16)((acc[i][j][r] + bi) * scale);
                }
            }
        __syncthreads();
        bf16* dst = (arr == 0) ? tR : fR;
        #pragma unroll
        for (int c = tid; c < 2048; c += 256) {
            const int pl = c >> 4, oo = c & 15;
            const int pg = p0 + pl;
            const int y = pg / 96, x = pg - y * 96;
            const int og = o0 + oo * 8;
            const int bh = b * 8 + (og >> 6), d = og & 63;
            const size_t di = (size_t)bh * BHS_ + (size_t)y * 6144 + x * 64 + d;
            *(uint4*)(dst + di) = *(const uint4*)&smem[pl * TS + oo * 8];
        }
    } else {
        // tileN[o_local][p_local]
        #pragma unroll
        for (int i = 0; i < 4; i++)
            #pragma unroll
            for (int r = 0; r < 4; r++) {
                const int ol_ = mrow + i * 16 + quad * 4 + r;
                const float bi = bias[o0 + ol_];
                #pragma unroll
                for (int j = 0; j < 4; j++) {
                    const int pl = ncol + j * 16 + l16;
                    smem[ol_ * TS + pl] = (bf16)(acc[i][j][r] + bi);
                }
            }
        __syncthreads();
        #pragma unroll
        for (int c = tid; c < 2048; c += 256) {
            const int ol_ = c >> 4, po = c & 15;
            const size_t di = (size_t)(b * 512 + o0 + ol_) * HW_ + p0 + po * 8;
            *(uint4*)(g + di) = *(const uint4*)&smem[ol_ * TS + po * 8];
        }
    }
}

// ---------------------------------------------------------------------------
// Kernel 2: plane transpose g -> gT (only g needs a transposed copy)
// grid (9 tiles, 2048 planes), block 256
// ---------------------------------------------------------------------------
__global__ __launch_bounds__(256) void transpose_g(const bf16* __restrict__ src, bf16* __restrict__ dst)
{
    const int plane = blockIdx.y;
    const int tile  = blockIdx.x;
    const int ty0 = (tile / 3) * 32, tx0 = (tile % 3) * 32;
    const bf16* s = src + (size_t)plane * HW_;
    bf16*       d = dst + (size_t)plane * HW_;

    __shared__ bf16 tb[32][33];
    const int tid = threadIdx.x;
    const int lx = tid & 31, lrow = tid >> 5;

    #pragma unroll
    for (int ss = 0; ss < 4; ss++) {
        int a = lrow + ss * 8;
        tb[a][lx] = s[(ty0 + a) * W_ + tx0 + lx];
    }
    __syncthreads();
    #pragma unroll
    for (int ss = 0; ss < 4; ss++) {
        int a = lrow + ss * 8;
        d[(tx0 + a) * H_ + ty0 + lx] = tb[lx][a];
    }
}

// ---------------------------------------------------------------------------
// Kernel 3: column attention.  Block (x, bh).  Stages tl/fl[j=y][d] by 128-B
// chunk gathers from tR/fR, gl[d][y'] from gT rows.  Diag mask at e-store.
// Writes outC[bh][x][y][d] (contiguous slice) + stats mc/lc[bh][x*96+y].
// ---------------------------------------------------------------------------
__global__ __launch_bounds__(256) void attn_col(
    const bf16* __restrict__ tR, const bf16* __restrict__ fR, const bf16* __restrict__ gT,
    bf16* __restrict__ outC, float* __restrict__ mc, float* __restrict__ lc)
{
    const int x = blockIdx.x;
    const int bh = blockIdx.y;

    __shared__ __align__(16) bf16 tl[96][72];
    __shared__ __align__(16) bf16 fl[96][72];
    __shared__ __align__(16) bf16 gl[64][104];
    __shared__ __align__(16) bf16 el[96][104];

    const int tid = threadIdx.x;
    const size_t sbase = (size_t)bh * BHS_;

    for (int i = tid; i < 768; i += 256) {
        const int y = i >> 3, oct = i & 7;
        const size_t gi = sbase + (size_t)y * 6144 + (size_t)x * 64 + oct * 8;
        *(uint4*)&tl[y][oct * 8] = *(const uint4*)(tR + gi);
        *(uint4*)&fl[y][oct * 8] = *(const uint4*)(fR + gi);
    }
    const size_t gbase = sbase + (size_t)x * 96;   // gT[bh][d][x][*y]
    for (int i = tid; i < 768; i += 256) {
        const int d = i / 12, seg = i % 12;
        *(uint4*)&gl[d][seg * 8] = *(const uint4*)(gT + gbase + (size_t)d * HW_ + seg * 8);
    }
    __syncthreads();

    const int lane = tid & 63, wave = tid >> 6;
    const int l16 = lane & 15, quad = lane >> 4;

    #pragma unroll
    for (int it = 0; it < 9; it++) {
        const int idx = wave + it * 4;
        const int mt = idx / 6, nt = idx % 6;
        floatx4 a = {};
        #pragma unroll
        for (int ks = 0; ks < 2; ks++) {
            bf16x8 af = *(const bf16x8*)&tl[mt * 16 + l16][ks * 32 + quad * 8];
            bf16x8 bf_ = *(const bf16x8*)&fl[nt * 16 + l16][ks * 32 + quad * 8];
            a = __builtin_amdgcn_mfma_f32_16x16x32_bf16(af, bf_, a, 0, 0, 0);
        }
        #pragma unroll
        for (int r = 0; r < 4; r++) {
            const int row = mt * 16 + quad * 4 + r, col = nt * 16 + l16;
            el[row][col] = (row == col) ? (bf16)(-1e30f) : (bf16)a[r];
        }
    }
    __syncthreads();

    // softmax: 2 threads per row, vectorized
    if (tid < 192) {
        const int r = tid >> 1, hf = tid & 1;
        float vals[48];
        float m = -1e30f;
        #pragma unroll
        for (int k = 0; k < 6; k++) {
            bf16x8 v8 = *(const bf16x8*)&el[r][hf * 48 + k * 8];
            #pragma unroll
            for (int e = 0; e < 8; e++) { vals[k * 8 + e] = (float)v8[e]; m = fmaxf(m, vals[k * 8 + e]); }
        }
        m = fmaxf(m, __shfl_xor(m, 1));
        float s = 0.f;
        #pragma unroll
        for (int k = 0; k < 6; k++) {
            bf16 tmp[8] __attribute__((aligned(16)));
            #pragma unroll
            for (int e = 0; e < 8; e++) {
                const float p = __expf(vals[k * 8 + e] - m);
                s += p; tmp[e] = (bf16)p;
            }
            *(uint4*)&el[r][hf * 48 + k * 8] = *(const uint4*)tmp;
        }
        s += __shfl_xor(s, 1);
        if (hf == 0) {
            mc[(size_t)bh * HW_ + x * 96 + r] = m;
            lc[(size_t)bh * HW_ + x * 96 + r] = s;
        }
    }
    __syncthreads();

    // PV: out[j=y][d], frags scattered into ol (overlays tl)
    bf16 (*ol)[72] = tl;
    #pragma unroll
    for (int it = 0; it < 6; it++) {
        const int idx = wave + it * 4;
        const int mt = idx >> 2, nt = idx & 3;
        floatx4 a = {};
        #pragma unroll
        for (int ks = 0; ks < 3; ks++) {
            bf16x8 pf = *(const bf16x8*)&el[mt * 16 + l16][ks * 32 + quad * 8];
            bf16x8 gf = *(const bf16x8*)&gl[nt * 16 + l16][ks * 32 + quad * 8];
            a = __builtin_amdgcn_mfma_f32_16x16x32_bf16(pf, gf, a, 0, 0, 0);
        }
        #pragma unroll
        for (int r = 0; r < 4; r++)
            ol[mt * 16 + quad * 4 + r][nt * 16 + l16] = (bf16)a[r];
    }
    __syncthreads();

    bf16* ob = outC + sbase + (size_t)x * 6144;
    for (int i = tid; i < 768; i += 256) {
        const int j = i >> 3, oct = i & 7;
        *(uint4*)(ob + (size_t)j * 64 + oct * 8) = *(const uint4*)&ol[j][oct * 8];
    }
}

// ---------------------------------------------------------------------------
// Kernel 4: row attention + fused merge.  Block (y, bh).  Contiguous staging
// from tR/fR, gl from g natural.  After PV, reads outC + col stats, merges,
// writes final fp32 output (gamma*val + v).
// ---------------------------------------------------------------------------
__global__ __launch_bounds__(256) void attn_row_merge(
    const bf16* __restrict__ tR, const bf16* __restrict__ fR, const bf16* __restrict__ g,
    const bf16* __restrict__ outC, const float* __restrict__ mc, const float* __restrict__ lc,
    const float* __restrict__ v, const float* __restrict__ gamma, float* __restrict__ out)
{
    const int y = blockIdx.x;
    const int bh = blockIdx.y;

    __shared__ __align__(16) bf16 tl[96][72];
    __shared__ __align__(16) bf16 fl[96][72];
    __shared__ __align__(16) bf16 gl[64][104];
    __shared__ __align__(16) bf16 el[96][104];
    __shared__ float mll[96], lll[96], wrl[96], wcl[96];

    const int tid = threadIdx.x;
    const size_t sbase = (size_t)bh * BHS_;
    const size_t slice = sbase + (size_t)y * 6144;

    for (int i = tid; i < 768; i += 256) {
        const int j = i >> 3, oct = i & 7;
        *(uint4*)&tl[j][oct * 8] = *(const uint4*)(tR + slice + (size_t)j * 64 + oct * 8);
        *(uint4*)&fl[j][oct * 8] = *(const uint4*)(fR + slice + (size_t)j * 64 + oct * 8);
    }
    const size_t gbase = sbase + (size_t)y * 96;   // g[bh][d][y][*x]
    for (int i = tid; i < 768; i += 256) {
        const int d = i / 12, seg = i % 12;
        *(uint4*)&gl[d][seg * 8] = *(const uint4*)(g + gbase + (size_t)d * HW_ + seg * 8);
    }
    __syncthreads();

    const int lane = tid & 63, wave = tid >> 6;
    const int l16 = lane & 15, quad = lane >> 4;

    #pragma unroll
    for (int it = 0; it < 9; it++) {
        const int idx = wave + it * 4;
        const int mt = idx / 6, nt = idx % 6;
        floatx4 a = {};
        #pragma unroll
        for (int ks = 0; ks < 2; ks++) {
            bf16x8 af = *(const bf16x8*)&tl[mt * 16 + l16][ks * 32 + quad * 8];
            bf16x8 bf_ = *(const bf16x8*)&fl[nt * 16 + l16][ks * 32 + quad * 8];
            a = __builtin_amdgcn_mfma_f32_16x16x32_bf16(af, bf_, a, 0, 0, 0);
        }
        #pragma unroll
        for (int r = 0; r < 4; r++)
            el[mt * 16 + quad * 4 + r][nt * 16 + l16] = (bf16)a[r];
    }
    __syncthreads();

    if (tid < 192) {
        const int r = tid >> 1, hf = tid & 1;
        float vals[48];
        float m = -1e30f;
        #pragma unroll
        for (int k = 0; k < 6; k++) {
            bf16x8 v8 = *(const bf16x8*)&el[r][hf * 48 + k * 8];
            #pragma unroll
            for (int e = 0; e < 8; e++) { vals[k * 8 + e] = (float)v8[e]; m = fmaxf(m, vals[k * 8 + e]); }
        }
        m = fmaxf(m, __shfl_xor(m, 1));
        float s = 0.f;
        #pragma unroll
        for (int k = 0; k < 6; k++) {
            bf16 tmp[8] __attribute__((aligned(16)));
            #pragma unroll
            for (int e = 0; e < 8; e++) {
                const float p = __expf(vals[k * 8 + e] - m);
                s += p; tmp[e] = (bf16)p;
            }
            *(uint4*)&el[r][hf * 48 + k * 8] = *(const uint4*)tmp;
        }
        s += __shfl_xor(s, 1);
        if (hf == 0) { mll[r] = m; lll[r] = s; }
    }
    __syncthreads();

    // phase: PV + merged-weight computation + ocl staging (independent work)
    if (tid < 96) {
        const float mrv = mll[tid], lrv = lll[tid];
        const float mcv = mc[(size_t)bh * HW_ + tid * 96 + y];
        const float lcv = lc[(size_t)bh * HW_ + tid * 96 + y];
        const float mm = fmaxf(mrv, mcv);
        const float wr = __expf(mrv - mm), wc = __expf(mcv - mm);
        const float dn = lrv * wr + lcv * wc;
        wrl[tid] = wr / dn;
        wcl[tid] = wc / dn;
    }
    bf16 (*ocl)[72] = fl;   // fl dead after e-GEMM
    for (int i = tid; i < 768; i += 256) {
        const int xx = i >> 3, oct = i & 7;
        *(uint4*)&ocl[xx][oct * 8] =
            *(const uint4*)(outC + sbase + (size_t)xx * 6144 + (size_t)y * 64 + oct * 8);
    }
    bf16 (*ol)[72] = tl;    // tl dead after e-GEMM
    #pragma unroll
    for (int it = 0; it < 6; it++) {
        const int idx = wave + it * 4;
        const int mt = idx >> 2, nt = idx & 3;
        floatx4 a = {};
        #pragma unroll
        for (int ks = 0; ks < 3; ks++) {
            bf16x8 pf = *(const bf16x8*)&el[mt * 16 + l16][ks * 32 + quad * 8];
            bf16x8 gf = *(const bf16x8*)&gl[nt * 16 + l16][ks * 32 + quad * 8];
            a = __builtin_amdgcn_mfma_f32_16x16x32_bf16(pf, gf, a, 0, 0, 0);
        }
        #pragma unroll
        for (int r = 0; r < 4; r++)
            ol[mt * 16 + quad * 4 + r][nt * 16 + l16] = (bf16)a[r];
    }
    __syncthreads();

    // merge + final output: items (xoct, d); lanes span d -> conflict-free LDS
    const float gam = gamma[0];
    for (int i = tid; i < 768; i += 256) {
        const int xo = i >> 6, d = i & 63;
        const int x0 = xo * 8;
        float res[8];
        #pragma unroll
        for (int k = 0; k < 8; k++) {
            const int xx = x0 + k;
            res[k] = (float)ol[xx][d] * wrl[xx] + (float)ocl[xx][d] * wcl[xx];
        }
        const size_t ob = sbase + (size_t)d * HW_ + (size_t)y * 96 + x0;
        const float4 v0 = *(const float4*)(v + ob);
        const float4 v1 = *(const float4*)(v + ob + 4);
        float4 r0, r1;
        r0.x = gam * res[0] + v0.x; r0.y = gam * res[1] + v0.y;
        r0.z = gam * res[2] + v0.z; r0.w = gam * res[3] + v0.w;
        r1.x = gam * res[4] + v1.x; r1.y = gam * res[5] + v1.y;
        r1.z = gam * res[6] + v1.z; r1.w = gam * res[7] + v1.w;
        *(float4*)(out + ob) = r0;
        *(float4*)(out + ob + 4) = r1;
    }
}

// ---------------------------------------------------------------------------
extern "C" void kernel_launch(void* const* d_in, const int* in_sizes, int n_in,
                              void* d_out, int out_size, void* d_ws, size_t ws_size,
                              hipStream_t stream)
{
    const float* q     = (const float*)d_in[0];
    const float* v     = (const float*)d_in[1];
    const float* Wq    = (const float*)d_in[2];
    const float* bq    = (const float*)d_in[3];
    const float* Wk    = (const float*)d_in[4];
    const float* bk    = (const float*)d_in[5];
    const float* Wv    = (const float*)d_in[6];
    const float* bv    = (const float*)d_in[7];
    const float* gamma = (const float*)d_in[8];
    float* out = (float*)d_out;

    char* w = (char*)d_ws;
    const size_t Tb = T_ELEMS * sizeof(bf16);   // 37,748,736 B per slot
    bf16* qbT  = (bf16*)(w + 0 * Tb);   // dead after conv -> reused by outC
    bf16* vbT  = (bf16*)(w + 1 * Tb);   // dead after conv -> reused by gT
    bf16* tR   = (bf16*)(w + 2 * Tb);
    bf16* fR   = (bf16*)(w + 3 * Tb);
    bf16* g    = (bf16*)(w + 4 * Tb);
    bf16* gT   = (bf16*)(w + 1 * Tb);
    bf16* outC = (bf16*)(w + 0 * Tb);
    bf16* Wb   = (bf16*)(w + 6 * Tb);                       // 1.57 MB
    float* mc  = (float*)(w + 6 * Tb + 1572864);
    float* lc  = mc + S_ELEMS;
    // high-water: 6*Tb + 1.57 MB + 2.36 MB = 230.4 MB

    cast_w  <<<dim3(768), 256, 0, stream>>>(Wq, Wk, Wv, Wb);
    cast_qv <<<dim3(144, 8, 8), 256, 0, stream>>>(q, v, qbT, vbT);
    conv_mfma<<<dim3(72, 4, 12), 256, 0, stream>>>(Wb, bq, bk, bv, qbT, vbT, tR, fR, g);
    transpose_g<<<dim3(9, 2048), 256, 0, stream>>>(g, gT);
    attn_col<<<dim3(96, BH_), 256, 0, stream>>>(tR, fR, gT, outC, mc, lc);
    attn_row_merge<<<dim3(96, BH_), 256, 0, stream>>>(tR, fR, g, outC, mc, lc, v, gamma, out);
}